// Round 3
// baseline (8131.402 us; speedup 1.0000x reference)
//
#include <hip/hip_runtime.h>
#include <hip/hip_fp16.h>

#define BM 64
#define BN 64
#define BK 16

typedef __half st_t;   // 2-byte storage type for large intermediates

__device__ __forceinline__ float s2f(st_t v) { return __half2float(v); }
__device__ __forceinline__ st_t f2s(float f) { return __float2half(f); }

// C[M,N] = relu( A1[M,K1] @ W1[N,K1]^T + A2[M,K2] @ W2[N,K2]^T + bias )
// A1: f32 (global input), A2: fp16 scratch (optional), C: fp16. Accumulate f32.
__global__ __launch_bounds__(256) void gemm2(
    const float* __restrict__ A1, int lda1, int K1, const float* __restrict__ W1, int ldw1,
    const st_t*  __restrict__ A2, int lda2, int K2, const float* __restrict__ W2, int ldw2,
    const float* __restrict__ bias, st_t* __restrict__ C, int M, int N)
{
    __shared__ float As[BK][BM + 1];
    __shared__ float Bs[BK][BN + 1];
    const int bm = blockIdx.x * BM;
    const int bn = blockIdx.y * BN;
    const int tid = threadIdx.x;
    const int tm = (tid / 16) * 4;
    const int tn = (tid % 16) * 4;

    float acc[4][4] = {};

    // pass 0: f32 A1
    for (int k0 = 0; k0 < K1; k0 += BK) {
        for (int e = tid; e < BM * BK; e += 256) {
            int row = e / BK, kk = e % BK;
            int gr = bm + row, gk = k0 + kk;
            As[kk][row] = (gr < M && gk < K1) ? A1[(size_t)gr * lda1 + gk] : 0.f;
        }
        for (int e = tid; e < BN * BK; e += 256) {
            int col = e / BK, kk = e % BK;
            int gc = bn + col, gk = k0 + kk;
            Bs[kk][col] = (gc < N && gk < K1) ? W1[(size_t)gc * ldw1 + gk] : 0.f;
        }
        __syncthreads();
        #pragma unroll
        for (int kk = 0; kk < BK; ++kk) {
            float a[4], b[4];
            #pragma unroll
            for (int i = 0; i < 4; ++i) a[i] = As[kk][tm + i];
            #pragma unroll
            for (int j = 0; j < 4; ++j) b[j] = Bs[kk][tn + j];
            #pragma unroll
            for (int i = 0; i < 4; ++i)
                #pragma unroll
                for (int j = 0; j < 4; ++j)
                    acc[i][j] += a[i] * b[j];
        }
        __syncthreads();
    }

    // pass 1: fp16 A2 (optional)
    if (A2 != nullptr) {
        for (int k0 = 0; k0 < K2; k0 += BK) {
            for (int e = tid; e < BM * BK; e += 256) {
                int row = e / BK, kk = e % BK;
                int gr = bm + row, gk = k0 + kk;
                As[kk][row] = (gr < M && gk < K2) ? s2f(A2[(size_t)gr * lda2 + gk]) : 0.f;
            }
            for (int e = tid; e < BN * BK; e += 256) {
                int col = e / BK, kk = e % BK;
                int gc = bn + col, gk = k0 + kk;
                Bs[kk][col] = (gc < N && gk < K2) ? W2[(size_t)gc * ldw2 + gk] : 0.f;
            }
            __syncthreads();
            #pragma unroll
            for (int kk = 0; kk < BK; ++kk) {
                float a[4], b[4];
                #pragma unroll
                for (int i = 0; i < 4; ++i) a[i] = As[kk][tm + i];
                #pragma unroll
                for (int j = 0; j < 4; ++j) b[j] = Bs[kk][tn + j];
                #pragma unroll
                for (int i = 0; i < 4; ++i)
                    #pragma unroll
                    for (int j = 0; j < 4; ++j)
                        acc[i][j] += a[i] * b[j];
            }
            __syncthreads();
        }
    }

    for (int i = 0; i < 4; ++i) {
        int gr = bm + tm + i;
        if (gr >= M) continue;
        #pragma unroll
        for (int j = 0; j < 4; ++j) {
            int gc = bn + tn + j;
            if (gc >= N) continue;
            float v = acc[i][j];
            if (bias) v += bias[gc];
            v = fmaxf(v, 0.f);
            C[(size_t)gr * N + gc] = f2s(v);
        }
    }
}

// dst[i,:] = sum_{j<10} src[idx[i,j], :]
// H=256 fp16: one row = 512 B = 32 lanes x float4. 8 rows per 256-thread block.
__global__ __launch_bounds__(256) void gather_sum10(
    const st_t* __restrict__ src, const int* __restrict__ idx,
    st_t* __restrict__ dst, int n_rows)
{
    int row  = blockIdx.x * 8 + (threadIdx.x >> 5);
    int lane = threadIdx.x & 31;           // 32 lanes x 16B = 512B = one row
    if (row >= n_rows) return;
    const int* ip = idx + (size_t)row * 10;
    float s[8] = {};
    #pragma unroll
    for (int j = 0; j < 10; ++j) {
        int r = ip[j];
        float4 v = *((const float4*)(src + (size_t)r * 256) + lane);
        const st_t* pb = (const st_t*)&v;
        #pragma unroll
        for (int e = 0; e < 8; ++e) s[e] += s2f(pb[e]);
    }
    st_t o[8];
    #pragma unroll
    for (int e = 0; e < 8; ++e) o[e] = f2s(s[e]);
    *((float4*)(dst + (size_t)row * 256) + lane) = *(const float4*)o;
}

// mol_h[m,:] = sum over atoms a with mol_idx[a]==m (sorted); fp16 -> f32
__global__ __launch_bounds__(256) void segsum(
    const st_t* __restrict__ atom_h, const int* __restrict__ mol_idx,
    float* __restrict__ mol_h, int n_atoms)
{
    int m = blockIdx.x;
    int lo = 0, hi = n_atoms;
    while (lo < hi) { int mid = (lo + hi) >> 1; if (mol_idx[mid] < m) lo = mid + 1; else hi = mid; }
    int start = lo;
    hi = n_atoms;
    while (lo < hi) { int mid = (lo + hi) >> 1; if (mol_idx[mid] < m + 1) lo = mid + 1; else hi = mid; }
    int end = lo;
    int c = threadIdx.x;
    float s = 0.f;
    for (int a = start; a < end; ++a) s += s2f(atom_h[(size_t)a * 256 + c]);
    mol_h[(size_t)m * 256 + c] = s;
}

__global__ __launch_bounds__(256) void diff_kernel(
    const float* __restrict__ a, const float* __restrict__ b,
    float* __restrict__ c, int n)
{
    int i = blockIdx.x * 256 + threadIdx.x;
    if (i < n) c[i] = a[i] - b[i];
}

// out[m] = dot(rxn[m,:], Wro[:]) + bro   (rxn fp16)
__global__ __launch_bounds__(256) void final_dot(
    const st_t* __restrict__ rxn, const float* __restrict__ Wro,
    const float* __restrict__ bro, float* __restrict__ out)
{
    int m = blockIdx.x;
    int t = threadIdx.x;
    float v = s2f(rxn[(size_t)m * 256 + t]) * Wro[t];
    #pragma unroll
    for (int off = 32; off; off >>= 1) v += __shfl_down(v, off, 64);
    __shared__ float red[4];
    if ((t & 63) == 0) red[t >> 6] = v;
    __syncthreads();
    if (t == 0) out[m] = red[0] + red[1] + red[2] + red[3] + bro[0];
}

static void run_graph(const float* fatoms, const float* fbonds, const int* agraph,
                      const int* bgraph, const int* mol_idx,
                      const float* Wi, const float* Wh, const float* Wo, const float* bo,
                      st_t* bufA, st_t* bufB, float* molh,
                      int n_atoms, int n_bonds, hipStream_t stream)
{
    dim3 gb((n_bonds + BM - 1) / BM, 256 / BN);
    dim3 ga((n_atoms + BM - 1) / BM, 256 / BN);

    // msg = relu(fbonds @ Wi^T)
    gemm2<<<gb, 256, 0, stream>>>(fbonds, 88, 88, Wi, 88,
                                  (const st_t*)nullptr, 0, 0, (const float*)nullptr, 0,
                                  (const float*)nullptr, bufA, n_bonds, 256);
    for (int it = 0; it < 3; ++it) {
        gather_sum10<<<(n_bonds + 7) / 8, 256, 0, stream>>>(bufA, bgraph, bufB, n_bonds);
        // msg = relu(fbonds@Wi^T + G@Wh^T)  (nei_input_h recomputed)
        gemm2<<<gb, 256, 0, stream>>>(fbonds, 88, 88, Wi, 88,
                                      bufB, 256, 256, Wh, 256,
                                      (const float*)nullptr, bufA, n_bonds, 256);
    }
    gather_sum10<<<(n_atoms + 7) / 8, 256, 0, stream>>>(bufA, agraph, bufB, n_atoms);
    // atom_h = relu(fatoms@Wo[:, :82]^T + atom_nei@Wo[:, 82:]^T + bo)
    gemm2<<<ga, 256, 0, stream>>>(fatoms, 82, 82, Wo, 338,
                                  bufB, 256, 256, Wo + 82, 338,
                                  bo, bufA, n_atoms, 256);
    segsum<<<2048, 256, 0, stream>>>(bufA, mol_idx, molh, n_atoms);
}

extern "C" void kernel_launch(void* const* d_in, const int* in_sizes, int n_in,
                              void* d_out, int out_size, void* d_ws, size_t ws_size,
                              hipStream_t stream)
{
    const float* fatoms_src = (const float*)d_in[0];
    const float* fbonds_src = (const float*)d_in[1];
    const int*   agraph_src = (const int*)d_in[2];
    const int*   bgraph_src = (const int*)d_in[3];
    const int*   mol_idx_src= (const int*)d_in[4];
    const float* fatoms_tgt = (const float*)d_in[5];
    const float* fbonds_tgt = (const float*)d_in[6];
    const int*   agraph_tgt = (const int*)d_in[7];
    const int*   bgraph_tgt = (const int*)d_in[8];
    const int*   mol_idx_tgt= (const int*)d_in[9];
    const float* Wi_s = (const float*)d_in[10];
    const float* Wh_s = (const float*)d_in[11];
    const float* Wo_s = (const float*)d_in[12];
    const float* bo_s = (const float*)d_in[13];
    const float* Wi_t = (const float*)d_in[14];
    const float* Wh_t = (const float*)d_in[15];
    const float* Wo_t = (const float*)d_in[16];
    const float* bo_t = (const float*)d_in[17];
    const float* Wrh  = (const float*)d_in[18];
    const float* brh  = (const float*)d_in[19];
    const float* Wro  = (const float*)d_in[20];
    const float* bro  = (const float*)d_in[21];

    const int n_atoms = in_sizes[0] / 82;
    const int n_bonds = in_sizes[1] / 88;
    const int H = 256, NM = 2048;

    // workspace (~211 MB):
    //   bufA : n_bonds*H fp16 (102.4 MB)
    //   bufB : n_bonds*H fp16 (102.4 MB)
    //   molS, molT, dbuf : NM*H f32 (2 MB each); rxn : NM*H fp16 (1 MB)
    char* ws = (char*)d_ws;
    size_t bondB = (size_t)n_bonds * H * sizeof(st_t);
    st_t*  bufA = (st_t*)ws;
    st_t*  bufB = (st_t*)(ws + bondB);
    float* molS = (float*)(ws + 2 * bondB);
    float* molT = molS + (size_t)NM * H;
    float* dbuf = molT + (size_t)NM * H;
    st_t*  rxn  = (st_t*)(dbuf + (size_t)NM * H);

    run_graph(fatoms_src, fbonds_src, agraph_src, bgraph_src, mol_idx_src,
              Wi_s, Wh_s, Wo_s, bo_s, bufA, bufB, molS, n_atoms, n_bonds, stream);
    run_graph(fatoms_tgt, fbonds_tgt, agraph_tgt, bgraph_tgt, mol_idx_tgt,
              Wi_t, Wh_t, Wo_t, bo_t, bufA, bufB, molT, n_atoms, n_bonds, stream);

    diff_kernel<<<(NM * H + 255) / 256, 256, 0, stream>>>(molT, molS, dbuf, NM * H);
    // rxn_h = relu(diff @ Wrh^T + brh)
    dim3 gr((NM + BM - 1) / BM, 256 / BN);
    gemm2<<<gr, 256, 0, stream>>>(dbuf, 256, 256, Wrh, 256,
                                  (const st_t*)nullptr, 0, 0, (const float*)nullptr, 0,
                                  brh, rxn, NM, 256);
    final_dot<<<NM, 256, 0, stream>>>(rxn, Wro, bro, (float*)d_out);
}

// Round 4
// 3128.246 us; speedup vs baseline: 2.5993x; 2.5993x over previous
//
#include <hip/hip_runtime.h>

typedef _Float16 f16;
using f16x8 = __attribute__((ext_vector_type(8))) _Float16;
using f32x4 = __attribute__((ext_vector_type(4))) float;

#define H 256
#define NM 2048

// ---------------------------------------------------------------------------
// stage 16 f32 -> 16 f16 with bounds (elements >= valid become 0). float2 loads
// (src rows only guaranteed 8B-aligned: ldw=338/82 are odd multiples of 2).
__device__ __forceinline__ void load16_f32(const float* __restrict__ src, int valid, f16* tmp)
{
    #pragma unroll
    for (int i = 0; i < 16; i += 2) {
        float x = 0.f, y = 0.f;
        if (i + 1 < valid) { float2 v = *(const float2*)(src + i); x = v.x; y = v.y; }
        else if (i < valid) { x = src[i]; }
        tmp[i] = (f16)x; tmp[i + 1] = (f16)y;
    }
}

// C[M,N] = relu( A1[M,K1] @ W1[N,K1]^T + A2[M,K2] @ W2[N,K2]^T + bias )
// A1 f32 (optional), A2 f16 (optional), W f32, C f16. f32 accumulate via MFMA.
// Tile 128x128, 4 waves (2x2), wave sub-tile 64x64 = 4x4 frags of 16x16, BK=32.
__global__ __launch_bounds__(256) void gemm_mfma(
    const float* __restrict__ A1, int lda1, int K1, const float* __restrict__ W1, int ldw1,
    const f16*  __restrict__ A2, int lda2, int K2, const float* __restrict__ W2, int ldw2,
    const float* __restrict__ bias, f16* __restrict__ C, int M, int N)
{
    __shared__ f16 As[128][32];
    __shared__ f16 Bs[128][32];

    const int bm = blockIdx.x * 128;
    const int bn = blockIdx.y * 128;
    const int tid  = threadIdx.x;
    const int wave = tid >> 6, lane = tid & 63;
    const int wr = wave >> 1, wc = wave & 1;   // 2x2 wave grid
    const int lrow = lane & 15;                // A-row / B-col / C-col within frag
    const int kg   = lane >> 4;                // k-group 0..3 (8 halfs each)

    // staging mapping: thread -> (row, 16-half chunk)
    const int srow = tid >> 1;
    const int sc   = (tid & 1) * 16;

    f32x4 acc[4][4];
    #pragma unroll
    for (int m = 0; m < 4; ++m)
        #pragma unroll
        for (int n = 0; n < 4; ++n)
            acc[m][n] = (f32x4){0.f, 0.f, 0.f, 0.f};

    #pragma unroll
    for (int pass = 0; pass < 2; ++pass) {
        if (pass == 0 && A1 == nullptr) continue;
        if (pass == 1 && A2 == nullptr) continue;
        const int K   = pass ? K2 : K1;
        const float* W = pass ? W2 : W1;
        const int ldw = pass ? ldw2 : ldw1;

        for (int k0 = 0; k0 < K; k0 += 32) {
            // ---- stage A tile [128][32] ----
            {
                int gr = bm + srow;
                f16 tmp[16];
                if (pass == 0) {
                    int valid = (gr < M) ? (K - (k0 + sc)) : 0;
                    load16_f32(A1 + (size_t)gr * lda1 + k0 + sc, valid, tmp);
                } else {
                    if (gr < M) {   // K2=256 multiple of 32: chunk fully valid
                        const f16* p = A2 + (size_t)gr * lda2 + k0 + sc;
                        *(float4*)tmp       = *(const float4*)p;
                        *(float4*)(tmp + 8) = *(const float4*)(p + 8);
                    } else {
                        #pragma unroll
                        for (int i = 0; i < 16; ++i) tmp[i] = (f16)0.f;
                    }
                }
                *(float4*)&As[srow][sc]     = *(float4*)tmp;
                *(float4*)&As[srow][sc + 8] = *(float4*)(tmp + 8);
            }
            // ---- stage B tile [128][32] from W rows (output cols) ----
            {
                int gwr = bn + srow;           // N is a multiple of 128 here
                f16 tmp[16];
                int valid = K - (k0 + sc);
                load16_f32(W + (size_t)gwr * ldw + k0 + sc, valid, tmp);
                *(float4*)&Bs[srow][sc]     = *(float4*)tmp;
                *(float4*)&Bs[srow][sc + 8] = *(float4*)(tmp + 8);
            }
            __syncthreads();

            f16x8 af[4], bf[4];
            #pragma unroll
            for (int m = 0; m < 4; ++m)
                af[m] = *(const f16x8*)&As[wr * 64 + m * 16 + lrow][kg * 8];
            #pragma unroll
            for (int n = 0; n < 4; ++n)
                bf[n] = *(const f16x8*)&Bs[wc * 64 + n * 16 + lrow][kg * 8];
            #pragma unroll
            for (int m = 0; m < 4; ++m)
                #pragma unroll
                for (int n = 0; n < 4; ++n)
                    acc[m][n] = __builtin_amdgcn_mfma_f32_16x16x32_f16(af[m], bf[n], acc[m][n], 0, 0, 0);
            __syncthreads();
        }
    }

    // epilogue: C/D layout col=lane&15, row=kg*4+reg (m89-verified)
    #pragma unroll
    for (int m = 0; m < 4; ++m) {
        #pragma unroll
        for (int n = 0; n < 4; ++n) {
            int gc = bn + wc * 64 + n * 16 + lrow;
            float bv = bias ? bias[gc] : 0.f;
            int gr0 = bm + wr * 64 + m * 16 + kg * 4;
            #pragma unroll
            for (int r = 0; r < 4; ++r) {
                int gr = gr0 + r;
                if (gr < M) C[(size_t)gr * N + gc] = (f16)fmaxf(acc[m][n][r] + bv, 0.f);
            }
        }
    }
}

// ---------------------------------------------------------------------------
// dst[i,:] = sum_{j<10} src[idx[i,j], :]   (H=256 f16: one row = 512B = 32 lanes x 16B)
__global__ __launch_bounds__(256) void gather_sum10(
    const f16* __restrict__ src, const int* __restrict__ idx,
    f16* __restrict__ dst, int n_rows)
{
    int row  = blockIdx.x * 8 + (threadIdx.x >> 5);
    int lane = threadIdx.x & 31;
    if (row >= n_rows) return;
    const int* ip = idx + (size_t)row * 10;
    float s[8] = {};
    #pragma unroll
    for (int j = 0; j < 10; ++j) {
        int r = ip[j];
        float4 v = *((const float4*)(src + (size_t)r * H) + lane);
        const f16* pb = (const f16*)&v;
        #pragma unroll
        for (int e = 0; e < 8; ++e) s[e] += (float)pb[e];
    }
    f16 o[8];
    #pragma unroll
    for (int e = 0; e < 8; ++e) o[e] = (f16)s[e];
    *((float4*)(dst + (size_t)row * H) + lane) = *(const float4*)o;
}

// mol_h[m,:] = sum over atoms a with mol_idx[a]==m (sorted); f16 -> f32
__global__ __launch_bounds__(256) void segsum(
    const f16* __restrict__ atom_h, const int* __restrict__ mol_idx,
    float* __restrict__ mol_h, int n_atoms)
{
    int m = blockIdx.x;
    int lo = 0, hi = n_atoms;
    while (lo < hi) { int mid = (lo + hi) >> 1; if (mol_idx[mid] < m) lo = mid + 1; else hi = mid; }
    int start = lo;
    hi = n_atoms;
    while (lo < hi) { int mid = (lo + hi) >> 1; if (mol_idx[mid] < m + 1) lo = mid + 1; else hi = mid; }
    int end = lo;
    int c = threadIdx.x;
    float s = 0.f;
    for (int a = start; a < end; ++a) s += (float)atom_h[(size_t)a * H + c];
    mol_h[(size_t)m * H + c] = s;
}

// diff -> f16 (feeds the rxn MFMA GEMM)
__global__ __launch_bounds__(256) void diff_kernel(
    const float* __restrict__ a, const float* __restrict__ b,
    f16* __restrict__ c, int n)
{
    int i = blockIdx.x * 256 + threadIdx.x;
    if (i < n) c[i] = (f16)(a[i] - b[i]);
}

// out[m] = dot(rxn[m,:], Wro[:]) + bro
__global__ __launch_bounds__(256) void final_dot(
    const f16* __restrict__ rxn, const float* __restrict__ Wro,
    const float* __restrict__ bro, float* __restrict__ out)
{
    int m = blockIdx.x;
    int t = threadIdx.x;
    float v = (float)rxn[(size_t)m * H + t] * Wro[t];
    #pragma unroll
    for (int off = 32; off; off >>= 1) v += __shfl_down(v, off, 64);
    __shared__ float red[4];
    if ((t & 63) == 0) red[t >> 6] = v;
    __syncthreads();
    if (t == 0) out[m] = red[0] + red[1] + red[2] + red[3] + bro[0];
}

// ---------------------------------------------------------------------------
static void run_graph(const float* fatoms, const float* fbonds, const int* agraph,
                      const int* bgraph, const int* mol_idx,
                      const float* Wi, const float* Wh, const float* Wo, const float* bo,
                      f16* bufA, f16* bufB, float* molh,
                      int n_atoms, int n_bonds, hipStream_t stream)
{
    dim3 gb((n_bonds + 127) / 128, 2);
    dim3 ga((n_atoms + 127) / 128, 2);

    // msg = relu(fbonds @ Wi^T)
    gemm_mfma<<<gb, 256, 0, stream>>>(fbonds, 88, 88, Wi, 88,
                                      (const f16*)nullptr, 0, 0, (const float*)nullptr, 0,
                                      (const float*)nullptr, bufA, n_bonds, H);
    for (int it = 0; it < 3; ++it) {
        gather_sum10<<<(n_bonds + 7) / 8, 256, 0, stream>>>(bufA, bgraph, bufB, n_bonds);
        // msg = relu(fbonds@Wi^T + G@Wh^T)   (nei_input_h recomputed)
        gemm_mfma<<<gb, 256, 0, stream>>>(fbonds, 88, 88, Wi, 88,
                                          bufB, H, H, Wh, H,
                                          (const float*)nullptr, bufA, n_bonds, H);
    }
    gather_sum10<<<(n_atoms + 7) / 8, 256, 0, stream>>>(bufA, agraph, bufB, n_atoms);
    // atom_h = relu(fatoms@Wo[:,:82]^T + atom_nei@Wo[:,82:]^T + bo)
    gemm_mfma<<<ga, 256, 0, stream>>>(fatoms, 82, 82, Wo, 338,
                                      bufB, H, H, Wo + 82, 338,
                                      bo, bufA, n_atoms, H);
    segsum<<<NM, 256, 0, stream>>>(bufA, mol_idx, molh, n_atoms);
}

extern "C" void kernel_launch(void* const* d_in, const int* in_sizes, int n_in,
                              void* d_out, int out_size, void* d_ws, size_t ws_size,
                              hipStream_t stream)
{
    const float* fatoms_src = (const float*)d_in[0];
    const float* fbonds_src = (const float*)d_in[1];
    const int*   agraph_src = (const int*)d_in[2];
    const int*   bgraph_src = (const int*)d_in[3];
    const int*   mol_idx_src= (const int*)d_in[4];
    const float* fatoms_tgt = (const float*)d_in[5];
    const float* fbonds_tgt = (const float*)d_in[6];
    const int*   agraph_tgt = (const int*)d_in[7];
    const int*   bgraph_tgt = (const int*)d_in[8];
    const int*   mol_idx_tgt= (const int*)d_in[9];
    const float* Wi_s = (const float*)d_in[10];
    const float* Wh_s = (const float*)d_in[11];
    const float* Wo_s = (const float*)d_in[12];
    const float* bo_s = (const float*)d_in[13];
    const float* Wi_t = (const float*)d_in[14];
    const float* Wh_t = (const float*)d_in[15];
    const float* Wo_t = (const float*)d_in[16];
    const float* bo_t = (const float*)d_in[17];
    const float* Wrh  = (const float*)d_in[18];
    const float* brh  = (const float*)d_in[19];
    const float* Wro  = (const float*)d_in[20];
    const float* bro  = (const float*)d_in[21];

    const int n_atoms = in_sizes[0] / 82;
    const int n_bonds = in_sizes[1] / 88;

    // workspace (~210 MB): bufA/bufB f16 bond-sized; molS/molT f32; dbuf16/rxn f16
    char* ws = (char*)d_ws;
    size_t bondB = (size_t)n_bonds * H * sizeof(f16);
    f16*   bufA = (f16*)ws;
    f16*   bufB = (f16*)(ws + bondB);
    float* molS = (float*)(ws + 2 * bondB);
    float* molT = molS + (size_t)NM * H;
    f16*   dbuf = (f16*)(molT + (size_t)NM * H);
    f16*   rxn  = dbuf + (size_t)NM * H;

    run_graph(fatoms_src, fbonds_src, agraph_src, bgraph_src, mol_idx_src,
              Wi_s, Wh_s, Wo_s, bo_s, bufA, bufB, molS, n_atoms, n_bonds, stream);
    run_graph(fatoms_tgt, fbonds_tgt, agraph_tgt, bgraph_tgt, mol_idx_tgt,
              Wi_t, Wh_t, Wo_t, bo_t, bufA, bufB, molT, n_atoms, n_bonds, stream);

    diff_kernel<<<(NM * H + 255) / 256, 256, 0, stream>>>(molT, molS, dbuf, NM * H);
    // rxn_h = relu(diff @ Wrh^T + brh)
    dim3 gr((NM + 127) / 128, 2);
    gemm_mfma<<<gr, 256, 0, stream>>>((const float*)nullptr, 0, 0, (const float*)nullptr, 0,
                                      dbuf, H, H, Wrh, H,
                                      brh, rxn, NM, H);
    final_dot<<<NM, 256, 0, stream>>>(rxn, Wro, bro, (float*)d_out);
}

// Round 5
// 2640.135 us; speedup vs baseline: 3.0799x; 1.1849x over previous
//
#include <hip/hip_runtime.h>

typedef _Float16 f16;
using f16x8 = __attribute__((ext_vector_type(8))) _Float16;
using f32x4 = __attribute__((ext_vector_type(4))) float;

#define H 256
#define NM 2048

// async 16B global -> LDS (wave-uniform LDS base + lane*16)
__device__ __forceinline__ void gload_lds16(const f16* g, f16* lds)
{
    __builtin_amdgcn_global_load_lds(
        (const __attribute__((address_space(1))) void*)g,
        (__attribute__((address_space(3))) void*)lds, 16, 0, 0);
}

// ---------------------------------------------------------------------------
// C[M,N] = relu( A1[M,K1r] @ W1[N,K1p]^T + A2[M,K2] @ W2[N,K2]^T + bias )
// A1 f32 (optional; staged with bounds, K zero-padded to K1p), W1/W2 f16
// K-padded (ldw == Kp), A2 f16 (optional, lda2 halfs), C f16, f32 MFMA accum.
// Tile 128x128, 4 waves (2x2), wave 64x64 = 4x4 frags 16x16x32, BK=64.
// LDS linear [128][64]; 16B-chunk XOR swizzle (chunk ^= row&7) applied on the
// global source address (gload) / ds_write position (reg path) and on the
// fragment read -> 2-way banks (free) instead of 16-way.
__global__ __launch_bounds__(256) void gemm_mfma(
    const float* __restrict__ A1, int lda1, int K1r,
    const f16*  __restrict__ W1, int K1p,
    const f16*  __restrict__ A2, int lda2, int K2,
    const f16*  __restrict__ W2,
    const float* __restrict__ bias, f16* __restrict__ C, int M, int N)
{
    __shared__ f16 As[128][64];
    __shared__ f16 Bs[128][64];

    const int bm = blockIdx.x * 128;
    const int bn = blockIdx.y * 128;
    const int tid  = threadIdx.x;
    const int wave = tid >> 6, lane = tid & 63;
    const int wr = wave >> 1, wc = wave & 1;
    const int lrow = lane & 15;
    const int kg   = lane >> 4;
    const int swz  = lrow & 7;          // fragment-read row swizzle

    // gload lane decomposition: 64 lanes x 16B = 8 rows x 8 chunks
    const int glr = lane >> 3;          // row within 8-row group (== row&7)
    const int glc = lane & 7;           // chunk within row
    const int gsc = glc ^ glr;          // swizzled source chunk

    f32x4 acc[4][4];
    #pragma unroll
    for (int m = 0; m < 4; ++m)
        #pragma unroll
        for (int n = 0; n < 4; ++n)
            acc[m][n] = (f32x4){0.f, 0.f, 0.f, 0.f};

    auto mfma_body = [&]() {
        #pragma unroll
        for (int ks = 0; ks < 2; ++ks) {
            f16x8 af[4], bf[4];
            const int cc = ((ks * 4 + kg) ^ swz) * 8;
            #pragma unroll
            for (int m = 0; m < 4; ++m)
                af[m] = *(const f16x8*)&As[wr * 64 + m * 16 + lrow][cc];
            #pragma unroll
            for (int n = 0; n < 4; ++n)
                bf[n] = *(const f16x8*)&Bs[wc * 64 + n * 16 + lrow][cc];
            #pragma unroll
            for (int m = 0; m < 4; ++m)
                #pragma unroll
                for (int n = 0; n < 4; ++n)
                    acc[m][n] = __builtin_amdgcn_mfma_f32_16x16x32_f16(af[m], bf[n], acc[m][n], 0, 0, 0);
        }
    };

    // ---- pass 0: f32 A1 (reg-staged, bounds) + f16 W1 (gload) ----
    if (A1 != nullptr) {
        for (int k0 = 0; k0 < K1p; k0 += 64) {
            {
                int row = tid >> 1;
                int h0  = (tid & 1) * 32;
                int gr  = bm + row;
                const float* srcp = A1 + (size_t)gr * lda1 + k0 + h0;
                f16 tmp[32];
                #pragma unroll
                for (int i = 0; i < 32; i += 2) {
                    float x = 0.f, y = 0.f;
                    int gk = k0 + h0 + i;
                    if (gr < M) {
                        if (gk + 1 < K1r) { float2 v = *(const float2*)(srcp + i); x = v.x; y = v.y; }
                        else if (gk < K1r) { x = srcp[i]; }
                    }
                    tmp[i] = (f16)x; tmp[i + 1] = (f16)y;
                }
                int rs = row & 7;
                int gb = h0 >> 3;
                #pragma unroll
                for (int j = 0; j < 4; ++j)
                    *(float4*)&As[row][((gb + j) ^ rs) * 8] = *(float4*)&tmp[j * 8];
            }
            #pragma unroll
            for (int q = 0; q < 4; ++q) {
                int row = wave * 32 + q * 8 + glr;
                gload_lds16(W1 + (size_t)(bn + row) * K1p + k0 + gsc * 8,
                            &Bs[wave * 32 + q * 8][0]);
            }
            __syncthreads();
            mfma_body();
            __syncthreads();
        }
    }

    // ---- pass 1: f16 A2 + f16 W2, both via gload ----
    if (A2 != nullptr) {
        for (int k0 = 0; k0 < K2; k0 += 64) {
            #pragma unroll
            for (int q = 0; q < 4; ++q) {
                int row = wave * 32 + q * 8 + glr;
                gload_lds16(A2 + (size_t)(bm + row) * lda2 + k0 + gsc * 8,
                            &As[wave * 32 + q * 8][0]);
                gload_lds16(W2 + (size_t)(bn + row) * K2 + k0 + gsc * 8,
                            &Bs[wave * 32 + q * 8][0]);
            }
            __syncthreads();
            mfma_body();
            __syncthreads();
        }
    }

    // epilogue: C/D layout col=lane&15, row=kg*4+reg (validated rounds 3-4)
    #pragma unroll
    for (int m = 0; m < 4; ++m) {
        #pragma unroll
        for (int n = 0; n < 4; ++n) {
            int gc = bn + wc * 64 + n * 16 + lrow;
            float bv = bias ? bias[gc] : 0.f;
            int gr0 = bm + wr * 64 + m * 16 + kg * 4;
            #pragma unroll
            for (int r = 0; r < 4; ++r) {
                int gr = gr0 + r;
                if (gr < M) C[(size_t)gr * N + gc] = (f16)fmaxf(acc[m][n][r] + bv, 0.f);
            }
        }
    }
}

// ---------------------------------------------------------------------------
// weight pre-convert: dst[n][k] = k < kvalid ? src[n*lds_+koff+k] : 0   (f16)
__global__ __launch_bounds__(256) void convert_w(
    const float* __restrict__ src, int lds_, int koff, int kvalid,
    f16* __restrict__ dst, int Kd)
{
    int n = blockIdx.x;
    for (int k = threadIdx.x; k < Kd; k += 256) {
        float v = (k < kvalid) ? src[(size_t)n * lds_ + koff + k] : 0.f;
        dst[(size_t)n * Kd + k] = (f16)v;
    }
}

// dst[i,:] = sum_{j<10} src[idx[i,j], :]  (row = 512B = 32 lanes x 16B)
__global__ __launch_bounds__(256) void gather_sum10(
    const f16* __restrict__ src, const int* __restrict__ idx,
    f16* __restrict__ dst, int n_rows)
{
    int row  = blockIdx.x * 8 + (threadIdx.x >> 5);
    int lane = threadIdx.x & 31;
    if (row >= n_rows) return;
    const int* ip = idx + (size_t)row * 10;
    float s[8] = {};
    #pragma unroll
    for (int j = 0; j < 10; ++j) {
        int r = ip[j];
        float4 v = *((const float4*)(src + (size_t)r * H) + lane);
        const f16* pb = (const f16*)&v;
        #pragma unroll
        for (int e = 0; e < 8; ++e) s[e] += (float)pb[e];
    }
    f16 o[8];
    #pragma unroll
    for (int e = 0; e < 8; ++e) o[e] = (f16)s[e];
    *((float4*)(dst + (size_t)row * H) + lane) = *(const float4*)o;
}

__global__ __launch_bounds__(256) void segsum(
    const f16* __restrict__ atom_h, const int* __restrict__ mol_idx,
    float* __restrict__ mol_h, int n_atoms)
{
    int m = blockIdx.x;
    int lo = 0, hi = n_atoms;
    while (lo < hi) { int mid = (lo + hi) >> 1; if (mol_idx[mid] < m) lo = mid + 1; else hi = mid; }
    int start = lo;
    hi = n_atoms;
    while (lo < hi) { int mid = (lo + hi) >> 1; if (mol_idx[mid] < m + 1) lo = mid + 1; else hi = mid; }
    int end = lo;
    int c = threadIdx.x;
    float s = 0.f;
    for (int a = start; a < end; ++a) s += (float)atom_h[(size_t)a * H + c];
    mol_h[(size_t)m * H + c] = s;
}

__global__ __launch_bounds__(256) void diff_kernel(
    const float* __restrict__ a, const float* __restrict__ b,
    f16* __restrict__ c, int n)
{
    int i = blockIdx.x * 256 + threadIdx.x;
    if (i < n) c[i] = (f16)(a[i] - b[i]);
}

__global__ __launch_bounds__(256) void final_dot(
    const f16* __restrict__ rxn, const float* __restrict__ Wro,
    const float* __restrict__ bro, float* __restrict__ out)
{
    int m = blockIdx.x;
    int t = threadIdx.x;
    float v = (float)rxn[(size_t)m * H + t] * Wro[t];
    #pragma unroll
    for (int off = 32; off; off >>= 1) v += __shfl_down(v, off, 64);
    __shared__ float red[4];
    if ((t & 63) == 0) red[t >> 6] = v;
    __syncthreads();
    if (t == 0) out[m] = red[0] + red[1] + red[2] + red[3] + bro[0];
}

// ---------------------------------------------------------------------------
static void run_graph(const float* fatoms, const float* fbonds, const int* agraph,
                      const int* bgraph, const int* mol_idx,
                      const f16* Wi16, const f16* Wh16, const f16* Wo1, const f16* Wo2,
                      const float* fbonds_f32, const float* bo,
                      f16* bufA, f16* bufB, float* molh,
                      int n_atoms, int n_bonds, hipStream_t stream)
{
    dim3 gb((n_bonds + 127) / 128, 2);
    dim3 ga((n_atoms + 127) / 128, 2);

    // msg0 = relu(fbonds @ Wi^T)
    gemm_mfma<<<gb, 256, 0, stream>>>(fbonds_f32, 88, 88, Wi16, 128,
                                      (const f16*)nullptr, 0, 0, (const f16*)nullptr,
                                      (const float*)nullptr, bufA, n_bonds, H);
    for (int it = 0; it < 3; ++it) {
        gather_sum10<<<(n_bonds + 7) / 8, 256, 0, stream>>>(bufA, bgraph, bufB, n_bonds);
        // msg = relu(fbonds@Wi^T + G@Wh^T)
        gemm_mfma<<<gb, 256, 0, stream>>>(fbonds_f32, 88, 88, Wi16, 128,
                                          bufB, H, H, Wh16,
                                          (const float*)nullptr, bufA, n_bonds, H);
    }
    gather_sum10<<<(n_atoms + 7) / 8, 256, 0, stream>>>(bufA, agraph, bufB, n_atoms);
    // atom_h = relu(fatoms@Wo[:,:82]^T + atom_nei@Wo[:,82:]^T + bo)
    gemm_mfma<<<ga, 256, 0, stream>>>(fatoms, 82, 82, Wo1, 128,
                                      bufB, H, H, Wo2,
                                      bo, bufA, n_atoms, H);
    segsum<<<NM, 256, 0, stream>>>(bufA, mol_idx, molh, n_atoms);
}

extern "C" void kernel_launch(void* const* d_in, const int* in_sizes, int n_in,
                              void* d_out, int out_size, void* d_ws, size_t ws_size,
                              hipStream_t stream)
{
    const float* fatoms_src = (const float*)d_in[0];
    const float* fbonds_src = (const float*)d_in[1];
    const int*   agraph_src = (const int*)d_in[2];
    const int*   bgraph_src = (const int*)d_in[3];
    const int*   mol_idx_src= (const int*)d_in[4];
    const float* fatoms_tgt = (const float*)d_in[5];
    const float* fbonds_tgt = (const float*)d_in[6];
    const int*   agraph_tgt = (const int*)d_in[7];
    const int*   bgraph_tgt = (const int*)d_in[8];
    const int*   mol_idx_tgt= (const int*)d_in[9];
    const float* Wi_s = (const float*)d_in[10];
    const float* Wh_s = (const float*)d_in[11];
    const float* Wo_s = (const float*)d_in[12];
    const float* bo_s = (const float*)d_in[13];
    const float* Wi_t = (const float*)d_in[14];
    const float* Wh_t = (const float*)d_in[15];
    const float* Wo_t = (const float*)d_in[16];
    const float* bo_t = (const float*)d_in[17];
    const float* Wrh  = (const float*)d_in[18];
    const float* brh  = (const float*)d_in[19];
    const float* Wro  = (const float*)d_in[20];
    const float* bro  = (const float*)d_in[21];

    const int n_atoms = in_sizes[0] / 82;
    const int n_bonds = in_sizes[1] / 88;

    // ---- workspace layout (~212 MB) ----
    char* ws = (char*)d_ws;
    size_t off = 0;
    auto alloc = [&](size_t bytes) { size_t o = off; off = (off + bytes + 255) & ~(size_t)255; return o; };
    f16*   bufA = (f16*)(ws + alloc((size_t)n_bonds * H * 2));
    f16*   bufB = (f16*)(ws + alloc((size_t)n_bonds * H * 2));
    float* molS = (float*)(ws + alloc((size_t)NM * H * 4));
    float* molT = (float*)(ws + alloc((size_t)NM * H * 4));
    f16*   dbuf = (f16*)(ws + alloc((size_t)NM * H * 2));
    f16*   rxn  = (f16*)(ws + alloc((size_t)NM * H * 2));
    f16* Wi16_s = (f16*)(ws + alloc(256 * 128 * 2));
    f16* Wh16_s = (f16*)(ws + alloc(256 * 256 * 2));
    f16* Wo1_s  = (f16*)(ws + alloc(256 * 128 * 2));
    f16* Wo2_s  = (f16*)(ws + alloc(256 * 256 * 2));
    f16* Wi16_t = (f16*)(ws + alloc(256 * 128 * 2));
    f16* Wh16_t = (f16*)(ws + alloc(256 * 256 * 2));
    f16* Wo1_t  = (f16*)(ws + alloc(256 * 128 * 2));
    f16* Wo2_t  = (f16*)(ws + alloc(256 * 256 * 2));
    f16* Wrh16  = (f16*)(ws + alloc(256 * 256 * 2));

    // ---- pre-convert weights to K-padded f16 (tiny) ----
    convert_w<<<256, 256, 0, stream>>>(Wi_s,  88,  0,  88, Wi16_s, 128);
    convert_w<<<256, 256, 0, stream>>>(Wh_s, 256,  0, 256, Wh16_s, 256);
    convert_w<<<256, 256, 0, stream>>>(Wo_s, 338,  0,  82, Wo1_s, 128);
    convert_w<<<256, 256, 0, stream>>>(Wo_s, 338, 82, 256, Wo2_s, 256);
    convert_w<<<256, 256, 0, stream>>>(Wi_t,  88,  0,  88, Wi16_t, 128);
    convert_w<<<256, 256, 0, stream>>>(Wh_t, 256,  0, 256, Wh16_t, 256);
    convert_w<<<256, 256, 0, stream>>>(Wo_t, 338,  0,  82, Wo1_t, 128);
    convert_w<<<256, 256, 0, stream>>>(Wo_t, 338, 82, 256, Wo2_t, 256);
    convert_w<<<256, 256, 0, stream>>>(Wrh, 256,  0, 256, Wrh16, 256);

    run_graph(fatoms_src, fbonds_src, agraph_src, bgraph_src, mol_idx_src,
              Wi16_s, Wh16_s, Wo1_s, Wo2_s, fbonds_src, bo_s,
              bufA, bufB, molS, n_atoms, n_bonds, stream);
    run_graph(fatoms_tgt, fbonds_tgt, agraph_tgt, bgraph_tgt, mol_idx_tgt,
              Wi16_t, Wh16_t, Wo1_t, Wo2_t, fbonds_tgt, bo_t,
              bufA, bufB, molT, n_atoms, n_bonds, stream);

    diff_kernel<<<(NM * H + 255) / 256, 256, 0, stream>>>(molT, molS, dbuf, NM * H);
    // rxn_h = relu(diff @ Wrh^T + brh)
    dim3 gr(NM / 128, 2);
    gemm_mfma<<<gr, 256, 0, stream>>>((const float*)nullptr, 0, 0, (const f16*)nullptr, 0,
                                      dbuf, H, H, Wrh16,
                                      brh, rxn, NM, H);
    final_dot<<<NM, 256, 0, stream>>>(rxn, Wro, bro, (float*)d_out);
}

// Round 6
// 2150.000 us; speedup vs baseline: 3.7820x; 1.2280x over previous
//
#include <hip/hip_runtime.h>

typedef _Float16 f16;
using f16x8 = __attribute__((ext_vector_type(8))) _Float16;
using f32x4 = __attribute__((ext_vector_type(4))) float;

#define H 256
#define NM 2048

// async 16B global -> LDS (wave-uniform LDS base + lane*16)
__device__ __forceinline__ void gload_lds16(const f16* g, f16* lds)
{
    __builtin_amdgcn_global_load_lds(
        (const __attribute__((address_space(1))) void*)g,
        (__attribute__((address_space(3))) void*)lds, 16, 0, 0);
}

// ---------------------------------------------------------------------------
// C[M,256] = relu( A1[M,K1r] @ W1[256,K1p]^T
//                + gather10(src2, idx2)[M,K2] @ W2[256,K2]^T + bias )
// A1 f32 (optional). src2 f16 (optional): if idx2 != null, A2 row i =
// sum_{j<10} src2[idx2[i][j], :] computed in staging; else direct rows.
// W1/W2 f16 K-padded. Tile 64 x 256, 4 waves (each 64x64), BK=64, f32 MFMA acc.
// LDS linear; 16B-chunk XOR swizzle (chunk ^= row&7) on write/source, matching
// fragment reads -> conflict-free reads (verified: SQ_LDS_BANK_CONFLICT == 0).
__global__ __launch_bounds__(256) void gemm_fused(
    const float* __restrict__ A1, int lda1, int K1r,
    const f16*  __restrict__ W1, int K1p,
    const f16*  __restrict__ src2, const int* __restrict__ idx2, int lda2,
    const f16*  __restrict__ W2, int K2,
    const float* __restrict__ bias, f16* __restrict__ C, int M)
{
    __shared__ f16 As[64][64];
    __shared__ f16 Bs[256][64];

    const int bm = blockIdx.x * 64;
    const int tid  = threadIdx.x;
    const int wave = tid >> 6, lane = tid & 63;
    const int lrow = lane & 15;
    const int kg   = lane >> 4;
    const int swz  = lrow & 7;

    // gload lane decomposition: 64 lanes x 16B = 8 rows x 8 chunks
    const int glr = lane >> 3;
    const int glc = lane & 7;
    const int gsc = glc ^ glr;          // swizzled source chunk

    // A staging decomposition: 4 threads per row, 16 halfs each
    const int arow = tid >> 2;
    const int aq   = tid & 3;
    const int ars  = arow & 7;

    f32x4 acc[4][4];
    #pragma unroll
    for (int m = 0; m < 4; ++m)
        #pragma unroll
        for (int n = 0; n < 4; ++n)
            acc[m][n] = (f32x4){0.f, 0.f, 0.f, 0.f};

    auto mfma_body = [&]() {
        #pragma unroll
        for (int ks = 0; ks < 2; ++ks) {
            f16x8 af[4], bf[4];
            const int cc = ((ks * 4 + kg) ^ swz) * 8;
            #pragma unroll
            for (int m = 0; m < 4; ++m)
                af[m] = *(const f16x8*)&As[m * 16 + lrow][cc];
            #pragma unroll
            for (int n = 0; n < 4; ++n)
                bf[n] = *(const f16x8*)&Bs[wave * 64 + n * 16 + lrow][cc];
            #pragma unroll
            for (int m = 0; m < 4; ++m)
                #pragma unroll
                for (int n = 0; n < 4; ++n)
                    acc[m][n] = __builtin_amdgcn_mfma_f32_16x16x32_f16(af[m], bf[n], acc[m][n], 0, 0, 0);
        }
    };

    auto stageB = [&](const f16* W, int ldw, int k0) {
        #pragma unroll
        for (int q = 0; q < 8; ++q)
            gload_lds16(W + (size_t)(wave * 64 + q * 8 + glr) * ldw + k0 + gsc * 8,
                        &Bs[wave * 64 + q * 8][0]);
    };

    // ---- pass 0: f32 A1 (reg-staged, bounds) ----
    if (A1 != nullptr) {
        for (int k0 = 0; k0 < K1p; k0 += 64) {
            {
                int gr = bm + arow;
                const float* srcp = A1 + (size_t)gr * lda1 + k0 + aq * 16;
                f16 tmp[16];
                #pragma unroll
                for (int i = 0; i < 16; i += 2) {
                    float x = 0.f, y = 0.f;
                    int gk = k0 + aq * 16 + i;
                    if (gr < M) {
                        if (gk + 1 < K1r) { float2 v = *(const float2*)(srcp + i); x = v.x; y = v.y; }
                        else if (gk < K1r) { x = srcp[i]; }
                    }
                    tmp[i] = (f16)x; tmp[i + 1] = (f16)y;
                }
                *(float4*)&As[arow][((aq * 2)     ^ ars) * 8] = *(float4*)&tmp[0];
                *(float4*)&As[arow][((aq * 2 + 1) ^ ars) * 8] = *(float4*)&tmp[8];
            }
            stageB(W1, K1p, k0);
            __syncthreads();
            mfma_body();
            __syncthreads();
        }
    }

    // ---- pass 1: gathered (or direct) f16 A2 ----
    if (src2 != nullptr) {
        for (int k0 = 0; k0 < K2; k0 += 64) {
            if (idx2 != nullptr) {
                int gr = bm + arow;
                f16 tmp[16];
                int ip[10];
                if (gr < M) {
                    const int* ipp = idx2 + (size_t)gr * 10;
                    #pragma unroll
                    for (int j = 0; j < 10; ++j) ip[j] = ipp[j];
                    // low 8 halfs
                    {
                        float s[8] = {};
                        #pragma unroll
                        for (int j = 0; j < 10; ++j) {
                            float4 v = *(const float4*)(src2 + (size_t)ip[j] * lda2 + k0 + aq * 16);
                            const f16* pb = (const f16*)&v;
                            #pragma unroll
                            for (int e = 0; e < 8; ++e) s[e] += (float)pb[e];
                        }
                        #pragma unroll
                        for (int e = 0; e < 8; ++e) tmp[e] = (f16)s[e];
                    }
                    // high 8 halfs
                    {
                        float s[8] = {};
                        #pragma unroll
                        for (int j = 0; j < 10; ++j) {
                            float4 v = *(const float4*)(src2 + (size_t)ip[j] * lda2 + k0 + aq * 16 + 8);
                            const f16* pb = (const f16*)&v;
                            #pragma unroll
                            for (int e = 0; e < 8; ++e) s[e] += (float)pb[e];
                        }
                        #pragma unroll
                        for (int e = 0; e < 8; ++e) tmp[8 + e] = (f16)s[e];
                    }
                } else {
                    #pragma unroll
                    for (int e = 0; e < 16; ++e) tmp[e] = (f16)0.f;
                }
                *(float4*)&As[arow][((aq * 2)     ^ ars) * 8] = *(float4*)&tmp[0];
                *(float4*)&As[arow][((aq * 2 + 1) ^ ars) * 8] = *(float4*)&tmp[8];
            } else {
                // direct rows (M must be a multiple of 64 in this mode)
                #pragma unroll
                for (int q = 0; q < 2; ++q)
                    gload_lds16(src2 + (size_t)(bm + wave * 16 + q * 8 + glr) * lda2 + k0 + gsc * 8,
                                &As[wave * 16 + q * 8][0]);
            }
            stageB(W2, K2, k0);
            __syncthreads();
            mfma_body();
            __syncthreads();
        }
    }

    // epilogue: C/D layout col=lane&15, row=kg*4+reg (validated rounds 3-5)
    #pragma unroll
    for (int n = 0; n < 4; ++n) {
        int gc = wave * 64 + n * 16 + lrow;
        float bv = bias ? bias[gc] : 0.f;
        #pragma unroll
        for (int m = 0; m < 4; ++m) {
            #pragma unroll
            for (int r = 0; r < 4; ++r) {
                int gr = bm + m * 16 + kg * 4 + r;
                if (gr < M) C[(size_t)gr * H + gc] = (f16)fmaxf(acc[m][n][r] + bv, 0.f);
            }
        }
    }
}

// ---------------------------------------------------------------------------
// weight pre-convert: dst[n][k] = k < kvalid ? src[n*lds_+koff+k] : 0   (f16)
__global__ __launch_bounds__(256) void convert_w(
    const float* __restrict__ src, int lds_, int koff, int kvalid,
    f16* __restrict__ dst, int Kd)
{
    int n = blockIdx.x;
    for (int k = threadIdx.x; k < Kd; k += 256) {
        float v = (k < kvalid) ? src[(size_t)n * lds_ + koff + k] : 0.f;
        dst[(size_t)n * Kd + k] = (f16)v;
    }
}

__global__ __launch_bounds__(256) void segsum(
    const f16* __restrict__ atom_h, const int* __restrict__ mol_idx,
    float* __restrict__ mol_h, int n_atoms)
{
    int m = blockIdx.x;
    int lo = 0, hi = n_atoms;
    while (lo < hi) { int mid = (lo + hi) >> 1; if (mol_idx[mid] < m) lo = mid + 1; else hi = mid; }
    int start = lo;
    hi = n_atoms;
    while (lo < hi) { int mid = (lo + hi) >> 1; if (mol_idx[mid] < m + 1) lo = mid + 1; else hi = mid; }
    int end = lo;
    int c = threadIdx.x;
    float s = 0.f;
    for (int a = start; a < end; ++a) s += (float)atom_h[(size_t)a * H + c];
    mol_h[(size_t)m * H + c] = s;
}

__global__ __launch_bounds__(256) void diff_kernel(
    const float* __restrict__ a, const float* __restrict__ b,
    f16* __restrict__ c, int n)
{
    int i = blockIdx.x * 256 + threadIdx.x;
    if (i < n) c[i] = (f16)(a[i] - b[i]);
}

__global__ __launch_bounds__(256) void final_dot(
    const f16* __restrict__ rxn, const float* __restrict__ Wro,
    const float* __restrict__ bro, float* __restrict__ out)
{
    int m = blockIdx.x;
    int t = threadIdx.x;
    float v = (float)rxn[(size_t)m * H + t] * Wro[t];
    #pragma unroll
    for (int off = 32; off; off >>= 1) v += __shfl_down(v, off, 64);
    __shared__ float red[4];
    if ((t & 63) == 0) red[t >> 6] = v;
    __syncthreads();
    if (t == 0) out[m] = red[0] + red[1] + red[2] + red[3] + bro[0];
}

// ---------------------------------------------------------------------------
static void run_graph(const float* fatoms, const float* fbonds, const int* agraph,
                      const int* bgraph, const int* mol_idx,
                      const f16* Wi16, const f16* Wh16, const f16* Wo1, const f16* Wo2,
                      const float* bo,
                      f16* bufA, f16* bufB, float* molh,
                      int n_atoms, int n_bonds, hipStream_t stream)
{
    dim3 gb((n_bonds + 63) / 64);
    dim3 ga((n_atoms + 63) / 64);

    // msg0 = relu(fbonds @ Wi^T)
    gemm_fused<<<gb, 256, 0, stream>>>(fbonds, 88, 88, Wi16, 128,
                                       (const f16*)nullptr, (const int*)nullptr, 0,
                                       (const f16*)nullptr, 0,
                                       (const float*)nullptr, bufA, n_bonds);
    f16* cur = bufA; f16* nxt = bufB;
    for (int it = 0; it < 3; ++it) {
        // msg = relu(fbonds@Wi^T + gather10(msg, bgraph)@Wh^T)   (fused)
        gemm_fused<<<gb, 256, 0, stream>>>(fbonds, 88, 88, Wi16, 128,
                                           cur, bgraph, H, Wh16, H,
                                           (const float*)nullptr, nxt, n_bonds);
        f16* t = cur; cur = nxt; nxt = t;
    }
    // atom_h = relu(fatoms@Wo[:,:82]^T + gather10(msg, agraph)@Wo[:,82:]^T + bo)
    gemm_fused<<<ga, 256, 0, stream>>>(fatoms, 82, 82, Wo1, 128,
                                       cur, agraph, H, Wo2, H,
                                       bo, nxt, n_atoms);
    segsum<<<NM, 256, 0, stream>>>(nxt, mol_idx, molh, n_atoms);
}

extern "C" void kernel_launch(void* const* d_in, const int* in_sizes, int n_in,
                              void* d_out, int out_size, void* d_ws, size_t ws_size,
                              hipStream_t stream)
{
    const float* fatoms_src = (const float*)d_in[0];
    const float* fbonds_src = (const float*)d_in[1];
    const int*   agraph_src = (const int*)d_in[2];
    const int*   bgraph_src = (const int*)d_in[3];
    const int*   mol_idx_src= (const int*)d_in[4];
    const float* fatoms_tgt = (const float*)d_in[5];
    const float* fbonds_tgt = (const float*)d_in[6];
    const int*   agraph_tgt = (const int*)d_in[7];
    const int*   bgraph_tgt = (const int*)d_in[8];
    const int*   mol_idx_tgt= (const int*)d_in[9];
    const float* Wi_s = (const float*)d_in[10];
    const float* Wh_s = (const float*)d_in[11];
    const float* Wo_s = (const float*)d_in[12];
    const float* bo_s = (const float*)d_in[13];
    const float* Wi_t = (const float*)d_in[14];
    const float* Wh_t = (const float*)d_in[15];
    const float* Wo_t = (const float*)d_in[16];
    const float* bo_t = (const float*)d_in[17];
    const float* Wrh  = (const float*)d_in[18];
    const float* brh  = (const float*)d_in[19];
    const float* Wro  = (const float*)d_in[20];
    const float* bro  = (const float*)d_in[21];

    const int n_atoms = in_sizes[0] / 82;
    const int n_bonds = in_sizes[1] / 88;

    // ---- workspace layout (~212 MB, same proven footprint) ----
    char* ws = (char*)d_ws;
    size_t off = 0;
    auto alloc = [&](size_t bytes) { size_t o = off; off = (off + bytes + 255) & ~(size_t)255; return o; };
    f16*   bufA = (f16*)(ws + alloc((size_t)n_bonds * H * 2));
    f16*   bufB = (f16*)(ws + alloc((size_t)n_bonds * H * 2));
    float* molS = (float*)(ws + alloc((size_t)NM * H * 4));
    float* molT = (float*)(ws + alloc((size_t)NM * H * 4));
    f16*   dbuf = (f16*)(ws + alloc((size_t)NM * H * 2));
    f16*   rxn  = (f16*)(ws + alloc((size_t)NM * H * 2));
    f16* Wi16_s = (f16*)(ws + alloc(256 * 128 * 2));
    f16* Wh16_s = (f16*)(ws + alloc(256 * 256 * 2));
    f16* Wo1_s  = (f16*)(ws + alloc(256 * 128 * 2));
    f16* Wo2_s  = (f16*)(ws + alloc(256 * 256 * 2));
    f16* Wi16_t = (f16*)(ws + alloc(256 * 128 * 2));
    f16* Wh16_t = (f16*)(ws + alloc(256 * 256 * 2));
    f16* Wo1_t  = (f16*)(ws + alloc(256 * 128 * 2));
    f16* Wo2_t  = (f16*)(ws + alloc(256 * 256 * 2));
    f16* Wrh16  = (f16*)(ws + alloc(256 * 256 * 2));

    // ---- pre-convert weights to K-padded f16 (tiny) ----
    convert_w<<<256, 256, 0, stream>>>(Wi_s,  88,  0,  88, Wi16_s, 128);
    convert_w<<<256, 256, 0, stream>>>(Wh_s, 256,  0, 256, Wh16_s, 256);
    convert_w<<<256, 256, 0, stream>>>(Wo_s, 338,  0,  82, Wo1_s, 128);
    convert_w<<<256, 256, 0, stream>>>(Wo_s, 338, 82, 256, Wo2_s, 256);
    convert_w<<<256, 256, 0, stream>>>(Wi_t,  88,  0,  88, Wi16_t, 128);
    convert_w<<<256, 256, 0, stream>>>(Wh_t, 256,  0, 256, Wh16_t, 256);
    convert_w<<<256, 256, 0, stream>>>(Wo_t, 338,  0,  82, Wo1_t, 128);
    convert_w<<<256, 256, 0, stream>>>(Wo_t, 338, 82, 256, Wo2_t, 256);
    convert_w<<<256, 256, 0, stream>>>(Wrh, 256,  0, 256, Wrh16, 256);

    run_graph(fatoms_src, fbonds_src, agraph_src, bgraph_src, mol_idx_src,
              Wi16_s, Wh16_s, Wo1_s, Wo2_s, bo_s,
              bufA, bufB, molS, n_atoms, n_bonds, stream);
    run_graph(fatoms_tgt, fbonds_tgt, agraph_tgt, bgraph_tgt, mol_idx_tgt,
              Wi16_t, Wh16_t, Wo1_t, Wo2_t, bo_t,
              bufA, bufB, molT, n_atoms, n_bonds, stream);

    diff_kernel<<<(NM * H + 255) / 256, 256, 0, stream>>>(molT, molS, dbuf, NM * H);
    // rxn_h = relu(diff @ Wrh^T + brh)   (direct-A2 mode, M=2048 = 32*64)
    gemm_fused<<<NM / 64, 256, 0, stream>>>((const float*)nullptr, 0, 0, (const f16*)nullptr, 0,
                                            dbuf, (const int*)nullptr, H, Wrh16, H,
                                            brh, rxn, NM);
    final_dot<<<NM, 256, 0, stream>>>(rxn, Wro, bro, (float*)d_out);
}